// Round 11
// baseline (289.192 us; speedup 1.0000x reference)
//
#include <hip/hip_runtime.h>
#include <math.h>

#define N_NODES 50000
#define N_EDGES 1600000
#define F 256
#define ALPHA 0.2f
#define NP 50048   // padded node count (multiple of 128)
#define NB 196     // coarse buckets: bucket = row >> 8 (256 rows each)
#define CAP 10240  // fixed bucket capacity (Poisson mean 8192, sigma 91 -> 22σ)
#define EPB 4096   // edges per binning block
#define NAB ((N_EDGES + EPB - 1) / EPB)  // 391
#define UNROLL 16
#define GEMM_BLOCKS 782  // (NP/128) * (F/128)
#define FVEC_BLOCKS ((N_NODES + 3) / 4)  // 12500

typedef short bf16x8 __attribute__((ext_vector_type(8)));
typedef float f32x4 __attribute__((ext_vector_type(4)));
typedef _Float16 half4 __attribute__((ext_vector_type(4)));

__device__ __forceinline__ unsigned short f2bf(float f) {
  union { float f; unsigned u; } v; v.f = f;
  unsigned u = v.u;
  return (unsigned short)((u + 0x7fffu + ((u >> 16) & 1u)) >> 16);
}

__device__ __forceinline__ unsigned short f2h_bits(float f) {
  union { _Float16 h; unsigned short u; } v;
  v.h = (_Float16)f;
  return v.u;
}

__device__ __forceinline__ float h_bits2f(unsigned short u) {
  union { _Float16 h; unsigned short u; } v;
  v.u = u;
  return (float)v.h;
}

// ---- L1: prep_w: W -> Wt bf16 transposed; wa = W @ a_halves; cb; zero gcur
__global__ __launch_bounds__(256) void prep_w(const float* __restrict__ W,
                                              const float* __restrict__ a_w,
                                              const float* __restrict__ W_b,
                                              const float* __restrict__ a_b,
                                              unsigned short* __restrict__ Wt,
                                              float* __restrict__ wa,
                                              float* __restrict__ cb,
                                              int* __restrict__ gcur) {
  if (blockIdx.x == 64) {  // zero the bucket cursors (replaces memset launch)
    if (threadIdx.x < NB) gcur[threadIdx.x] = 0;
    return;
  }
  const int lane = threadIdx.x & 63, w = threadIdx.x >> 6;
  const int k = blockIdx.x * 4 + w;  // 0..255
  float4 wv = *(const float4*)(W + (size_t)k * F + lane * 4);
  float4 a1 = *(const float4*)(a_w + lane * 4);
  float4 a2 = *(const float4*)(a_w + F + lane * 4);
  Wt[(size_t)(lane * 4 + 0) * F + k] = f2bf(wv.x);
  Wt[(size_t)(lane * 4 + 1) * F + k] = f2bf(wv.y);
  Wt[(size_t)(lane * 4 + 2) * F + k] = f2bf(wv.z);
  Wt[(size_t)(lane * 4 + 3) * F + k] = f2bf(wv.w);
  float s1 = wv.x * a1.x + wv.y * a1.y + wv.z * a1.z + wv.w * a1.w;
  float s2 = wv.x * a2.x + wv.y * a2.y + wv.z * a2.z + wv.w * a2.w;
#pragma unroll
  for (int off = 32; off > 0; off >>= 1) {
    s1 += __shfl_down(s1, off, 64);
    s2 += __shfl_down(s2, off, 64);
  }
  if (lane == 0) { wa[k] = s1; wa[F + k] = s2; }
  if (blockIdx.x == 0 && w == 0) {
    float4 b = *(const float4*)(W_b + lane * 4);
    float t1 = b.x * (a1.x + a2.x) + b.y * (a1.y + a2.y) +
               b.z * (a1.z + a2.z) + b.w * (a1.w + a2.w);
#pragma unroll
    for (int off = 32; off > 0; off >>= 1) t1 += __shfl_down(t1, off, 64);
    if (lane == 0) cb[0] = t1 + a_b[0];
  }
}

// ---- L2: fused GEMM [0,782) + binA2 [782,1173) + fvec2 [1173,...)
// GEMM stages x fp32 -> bf16 inline (no x_bf dependency); binA2 groups edges
// into fixed-capacity bucket regions; fvec2 computes f_dst/f_row projections.
#define LDSK 72
__global__ __launch_bounds__(256) void gemm_fvec_binA2(
    const float* __restrict__ x,
    const unsigned short* __restrict__ Wt,
    const float* __restrict__ bias,
    const float* __restrict__ wa,
    const int* __restrict__ row,
    const int* __restrict__ col,
    _Float16* __restrict__ Wh,
    float* __restrict__ f_dst,
    float* __restrict__ f_row,
    int* __restrict__ gcur,
    unsigned* __restrict__ gstage) {
  __shared__ char smem[2 * 128 * LDSK * 2];  // 36864 B arena
  if (blockIdx.x < GEMM_BLOCKS) {
    // ---- GEMM part: Wh(fp16) = bf16(x) @ Wt^T + bias
    short* As = (short*)smem;
    short* Bs = As + 128 * LDSK;
    const int tid = threadIdx.x;
    const int lane = tid & 63;
    const int w = tid >> 6;
    const int wm = w >> 1, wn = w & 1;
    const int m0 = (blockIdx.x >> 1) * 128;
    const int n0 = (blockIdx.x & 1) * 128;
    f32x4 acc[4][4] = {{{0.f, 0.f, 0.f, 0.f}}};
    const int srow = tid >> 3;   // 0..31
    const int schunk = tid & 7;  // 0..7
    for (int k0 = 0; k0 < F; k0 += 64) {
#pragma unroll
      for (int i = 0; i < 4; ++i) {
        int r = i * 32 + srow;
        int gm = m0 + r; if (gm > N_NODES - 1) gm = N_NODES - 1;
        const float* src = x + (size_t)gm * F + k0 + schunk * 8;
        float4 lo = *(const float4*)src;
        float4 hi = *(const float4*)(src + 4);
        bf16x8 v;
        v[0] = (short)f2bf(lo.x); v[1] = (short)f2bf(lo.y);
        v[2] = (short)f2bf(lo.z); v[3] = (short)f2bf(lo.w);
        v[4] = (short)f2bf(hi.x); v[5] = (short)f2bf(hi.y);
        v[6] = (short)f2bf(hi.z); v[7] = (short)f2bf(hi.w);
        *(bf16x8*)&As[r * LDSK + schunk * 8] = v;
        *(bf16x8*)&Bs[r * LDSK + schunk * 8] =
            *(const bf16x8*)(Wt + (size_t)(n0 + r) * F + k0 + schunk * 8);
      }
      __syncthreads();
#pragma unroll
      for (int kk = 0; kk < 64; kk += 32) {
        const int rowsel = lane & 15;
        const int ksel = kk + (lane >> 4) * 8;
        bf16x8 af[4], bfr[4];
#pragma unroll
        for (int t = 0; t < 4; ++t) {
          af[t] = *(bf16x8*)&As[(wm * 64 + t * 16 + rowsel) * LDSK + ksel];
          bfr[t] = *(bf16x8*)&Bs[(wn * 64 + t * 16 + rowsel) * LDSK + ksel];
        }
#pragma unroll
        for (int mi = 0; mi < 4; ++mi)
#pragma unroll
          for (int nj = 0; nj < 4; ++nj)
            acc[mi][nj] = __builtin_amdgcn_mfma_f32_16x16x32_bf16(
                af[mi], bfr[nj], acc[mi][nj], 0, 0, 0);
      }
      __syncthreads();
    }
    const int crow = (lane >> 4) * 4;
    const int ccol = lane & 15;
#pragma unroll
    for (int nj = 0; nj < 4; ++nj) {
      int gc = n0 + wn * 64 + nj * 16 + ccol;
      float bv = bias[gc];
#pragma unroll
      for (int mi = 0; mi < 4; ++mi) {
        int gr = m0 + wm * 64 + mi * 16 + crow;
#pragma unroll
        for (int r = 0; r < 4; ++r)
          Wh[(size_t)(gr + r) * F + gc] = (_Float16)(acc[mi][nj][r] + bv);
      }
    }
    return;
  }
  if (blockIdx.x < GEMM_BLOCKS + NAB) {
    // ---- binA2 part
    int* h = (int*)smem;
    int* lofs = h + NB;
    int* lcur = lofs + NB;
    int* gb = lcur + NB;
    unsigned* stage = (unsigned*)(gb + NB);  // EPB entries
    const int t = threadIdx.x;
    for (int i = t; i < NB; i += 256) { h[i] = 0; lcur[i] = 0; }
    __syncthreads();
    const int base = (blockIdx.x - GEMM_BLOCKS) * EPB;
    const int cnt = min(EPB, N_EDGES - base);
#pragma unroll
    for (int j = 0; j < 16; ++j) {
      int k = base + j * 256 + t;
      if (k < N_EDGES) atomicAdd(&h[row[k] >> 8], 1);
    }
    __syncthreads();
    if (t == 0) {
      int run = 0;
      for (int i = 0; i < NB; ++i) { lofs[i] = run; run += h[i]; }
    }
    __syncthreads();
    if (t < NB && h[t] > 0) gb[t] = atomicAdd(&gcur[t], h[t]);
    __syncthreads();
#pragma unroll
    for (int j = 0; j < 16; ++j) {
      int k = base + j * 256 + t;
      if (k < N_EDGES) {
        int r = row[k], b = r >> 8;
        int lp = lofs[b] + atomicAdd(&lcur[b], 1);
        stage[lp] = ((unsigned)b << 24) | ((unsigned)(r & 255) << 16) |
                    (unsigned)col[k];
      }
    }
    __syncthreads();
#pragma unroll
    for (int j = 0; j < 16; ++j) {
      int s = j * 256 + t;
      if (s < cnt) {
        unsigned wv = stage[s];
        int b = wv >> 24;
        gstage[(size_t)b * CAP + gb[b] + (s - lofs[b])] = wv & 0x00FFFFFFu;
      }
    }
    return;
  }
  // ---- fvec2 part: fp32 attention projections from x
  const int lane = threadIdx.x & 63, w = threadIdx.x >> 6;
  const int node = (blockIdx.x - GEMM_BLOCKS - NAB) * 4 + w;
  if (node >= N_NODES) return;
  float4 xv = *(const float4*)(x + (size_t)node * F + lane * 4);
  float4 v1 = *(const float4*)(wa + lane * 4);
  float4 v2 = *(const float4*)(wa + F + lane * 4);
  float s1 = xv.x * v1.x + xv.y * v1.y + xv.z * v1.z + xv.w * v1.w;
  float s2 = xv.x * v2.x + xv.y * v2.y + xv.z * v2.z + xv.w * v2.w;
#pragma unroll
  for (int off = 32; off > 0; off >>= 1) {
    s1 += __shfl_down(s1, off, 64);
    s2 += __shfl_down(s2, off, 64);
  }
  if (lane == 0) { f_dst[node] = s1; f_row[node] = s2; }
}

// ---- L3: binB (512 threads): per-row counts -> (start,count); exp weight
// once per EDGE packed (exw_fp16<<16 | col); per-row denom -> inv_denom.
__global__ __launch_bounds__(512) void binB(const int* __restrict__ gcur,
                                            const unsigned* __restrict__ gstage,
                                            const float* __restrict__ f_dst,
                                            const float* __restrict__ f_row,
                                            const float* __restrict__ cb,
                                            int2* __restrict__ rsc,
                                            float* __restrict__ inv_denom,
                                            unsigned* __restrict__ csr) {
  __shared__ int cnt[256], cur[256];
  __shared__ float dsum[256];
  const int t = threadIdx.x;
  const int b = blockIdx.x;
  if (t < 256) { cnt[t] = 0; dsum[t] = 0.f; }
  __syncthreads();
  const int nb = gcur[b];
  const int start = b * CAP;
  const float cbs = cb[0];
  for (int s = t; s < nb; s += 512) {
    unsigned wv = gstage[start + s];
    atomicAdd(&cnt[(wv >> 16) & 255], 1);
  }
  __syncthreads();
  if (t == 0) {
    int run = 0;
    for (int i = 0; i < 256; ++i) { int v = cnt[i]; cur[i] = run; run += v; }
  }
  __syncthreads();
  if (t < 256) {
    int g = (b << 8) + t;
    if (g < N_NODES) rsc[g] = make_int2(start + cur[t], cnt[t]);
  }
  __syncthreads();
  for (int s = t; s < nb; s += 512) {
    unsigned wv = gstage[start + s];
    int lr = (wv >> 16) & 255;
    int c = wv & 0xFFFF;
    float ev = f_dst[c] + f_row[(b << 8) + lr] + cbs;
    ev = ev > 0.f ? ev : ALPHA * ev;
    float ex = __expf(ev);
    int p = start + atomicAdd(&cur[lr], 1);
    csr[p] = ((unsigned)f2h_bits(ex) << 16) | (unsigned)c;
    atomicAdd(&dsum[lr], ex);
  }
  __syncthreads();
  if (t < 256) {
    int g = (b << 8) + t;
    if (g < N_NODES) inv_denom[g] = (cnt[t] > 0) ? (1.0f / dsum[t]) : 0.f;
  }
}

// ---- L4: pull: unrolled gather; weights + denom pre-baked; (start,count).
__global__ __launch_bounds__(256) void gat_pull(const int2* __restrict__ rsc,
                                                const unsigned* __restrict__ csr,
                                                const float* __restrict__ inv_denom,
                                                const _Float16* __restrict__ Wh,
                                                float* __restrict__ out) {
  const int lane = threadIdx.x & 63, w = threadIdx.x >> 6;
  const int i = blockIdx.x * 4 + w;
  if (i >= N_NODES) return;
  const int2 rc = rsc[i];
  const int s = rc.x, e = rc.x + rc.y;
  const char* whb = (const char*)Wh;
  const unsigned laneoff = (unsigned)lane * 8u;
  float4 acc = make_float4(0.f, 0.f, 0.f, 0.f);
  for (int p = s; p < e; p += UNROLL) {
    unsigned wv[UNROLL];
#pragma unroll
    for (int j = 0; j < UNROLL; ++j) {
      int q = p + j;
      wv[j] = csr[q < e ? q : s];  // clamp: redundant loads hit L1
    }
    half4 v[UNROLL];
#pragma unroll
    for (int j = 0; j < UNROLL; ++j) {
      unsigned off = (wv[j] & 0xFFFFu) * 512u + laneoff;  // 32-bit addressing
      v[j] = *(const half4*)(whb + off);
    }
#pragma unroll
    for (int j = 0; j < UNROLL; ++j) {
      float xw = h_bits2f((unsigned short)(wv[j] >> 16));
      xw = (p + j < e) ? xw : 0.f;
      acc.x += xw * (float)v[j][0];
      acc.y += xw * (float)v[j][1];
      acc.z += xw * (float)v[j][2];
      acc.w += xw * (float)v[j][3];
    }
  }
  const float inv = inv_denom[i];
  acc.x = fmaxf(acc.x * inv, 0.f); acc.y = fmaxf(acc.y * inv, 0.f);
  acc.z = fmaxf(acc.z * inv, 0.f); acc.w = fmaxf(acc.w * inv, 0.f);
  ((float4*)out)[(size_t)i * 64 + lane] = acc;
}

extern "C" void kernel_launch(void* const* d_in, const int* in_sizes, int n_in,
                              void* d_out, int out_size, void* d_ws, size_t ws_size,
                              hipStream_t stream) {
  const float* x   = (const float*)d_in[0];
  const float* W_w = (const float*)d_in[1];
  const float* W_b = (const float*)d_in[2];
  const float* a_w = (const float*)d_in[3];
  const float* a_b = (const float*)d_in[4];
  const int*   row = (const int*)d_in[5];
  const int*   col = (const int*)d_in[6];
  float* out = (float*)d_out;

  float* ws = (float*)d_ws;
  size_t off = 0;
  _Float16* Wh = (_Float16*)(ws + off); off += (size_t)NP * F / 2;       // fp16
  unsigned short* Wt = (unsigned short*)(ws + off); off += (F * F) / 2;  // bf16
  float* wa = ws + off;            off += 2 * F;
  float* cb = ws + off;            off += 8;
  float* f_dst = ws + off;         off += NP;
  float* f_row = ws + off;         off += NP;
  int* gcur = (int*)(ws + off);    off += NB;
  int2* rsc = (int2*)(ws + off);   off += 2 * (size_t)NP;
  float* inv_denom = (float*)(ws + off); off += NP;
  unsigned* gstage = (unsigned*)(ws + off); off += (size_t)NB * CAP;
  unsigned* csr = (unsigned*)(ws + off); off += (size_t)NB * CAP;
  (void)ws_size; (void)in_sizes; (void)n_in; (void)out_size;

  hipLaunchKernelGGL(prep_w, dim3(65), dim3(256), 0, stream, W_w, a_w, W_b,
                     a_b, Wt, wa, cb, gcur);
  hipLaunchKernelGGL(gemm_fvec_binA2, dim3(GEMM_BLOCKS + NAB + FVEC_BLOCKS),
                     dim3(256), 0, stream, x, Wt, W_b, wa, row, col, Wh,
                     f_dst, f_row, gcur, gstage);
  hipLaunchKernelGGL(binB, dim3(NB), dim3(512), 0, stream, gcur, gstage,
                     f_dst, f_row, cb, rsc, inv_denom, csr);
  hipLaunchKernelGGL(gat_pull, dim3((N_NODES + 3) / 4), dim3(256), 0, stream,
                     rsc, csr, inv_denom, Wh, out);
}

// Round 12
// 281.476 us; speedup vs baseline: 1.0274x; 1.0274x over previous
//
#include <hip/hip_runtime.h>
#include <math.h>

#define N_NODES 50000
#define N_EDGES 1600000
#define F 256
#define ALPHA 0.2f
#define NP 50048   // padded node count (multiple of 128)
#define NB 196     // coarse buckets: bucket = row >> 8 (256 rows each)
#define CAP 10240  // fixed bucket capacity (Poisson mean 8192, sigma 91 -> 22σ)
#define EPB 4096   // edges per binning block
#define NAB ((N_EDGES + EPB - 1) / EPB)  // 391
#define UNROLL 16
#define GEMM_BLOCKS 782  // (NP/128) * (F/128)
#define FVEC_SLOTS 2048  // grid-stride fat blocks for the projection part

typedef short bf16x8 __attribute__((ext_vector_type(8)));
typedef float f32x4 __attribute__((ext_vector_type(4)));
typedef _Float16 half4 __attribute__((ext_vector_type(4)));

__device__ __forceinline__ unsigned short f2bf(float f) {
  union { float f; unsigned u; } v; v.f = f;
  unsigned u = v.u;
  return (unsigned short)((u + 0x7fffu + ((u >> 16) & 1u)) >> 16);
}

__device__ __forceinline__ unsigned short f2h_bits(float f) {
  union { _Float16 h; unsigned short u; } v;
  v.h = (_Float16)f;
  return v.u;
}

__device__ __forceinline__ float h_bits2f(unsigned short u) {
  union { _Float16 h; unsigned short u; } v;
  v.u = u;
  return (float)v.h;
}

// ---- L1: prep_w: W -> Wt bf16 transposed; wa = W @ a_halves; cb; zero gcur
__global__ __launch_bounds__(256) void prep_w(const float* __restrict__ W,
                                              const float* __restrict__ a_w,
                                              const float* __restrict__ W_b,
                                              const float* __restrict__ a_b,
                                              unsigned short* __restrict__ Wt,
                                              float* __restrict__ wa,
                                              float* __restrict__ cb,
                                              int* __restrict__ gcur) {
  if (blockIdx.x == 64) {  // zero the bucket cursors (replaces memset launch)
    if (threadIdx.x < NB) gcur[threadIdx.x] = 0;
    return;
  }
  const int lane = threadIdx.x & 63, w = threadIdx.x >> 6;
  const int k = blockIdx.x * 4 + w;  // 0..255
  float4 wv = *(const float4*)(W + (size_t)k * F + lane * 4);
  float4 a1 = *(const float4*)(a_w + lane * 4);
  float4 a2 = *(const float4*)(a_w + F + lane * 4);
  Wt[(size_t)(lane * 4 + 0) * F + k] = f2bf(wv.x);
  Wt[(size_t)(lane * 4 + 1) * F + k] = f2bf(wv.y);
  Wt[(size_t)(lane * 4 + 2) * F + k] = f2bf(wv.z);
  Wt[(size_t)(lane * 4 + 3) * F + k] = f2bf(wv.w);
  float s1 = wv.x * a1.x + wv.y * a1.y + wv.z * a1.z + wv.w * a1.w;
  float s2 = wv.x * a2.x + wv.y * a2.y + wv.z * a2.z + wv.w * a2.w;
#pragma unroll
  for (int off = 32; off > 0; off >>= 1) {
    s1 += __shfl_down(s1, off, 64);
    s2 += __shfl_down(s2, off, 64);
  }
  if (lane == 0) { wa[k] = s1; wa[F + k] = s2; }
  if (blockIdx.x == 0 && w == 0) {
    float4 b = *(const float4*)(W_b + lane * 4);
    float t1 = b.x * (a1.x + a2.x) + b.y * (a1.y + a2.y) +
               b.z * (a1.z + a2.z) + b.w * (a1.w + a2.w);
#pragma unroll
    for (int off = 32; off > 0; off >>= 1) t1 += __shfl_down(t1, off, 64);
    if (lane == 0) cb[0] = t1 + a_b[0];
  }
}

// ---- L2: fused GEMM [0,782) + binA2 [782,1173) + fvec [1173,1173+2048)
#define LDSK 72
__global__ __launch_bounds__(256) void gemm_fvec_binA2(
    const float* __restrict__ x,
    const unsigned short* __restrict__ Wt,
    const float* __restrict__ bias,
    const float* __restrict__ wa,
    const int* __restrict__ row,
    const int* __restrict__ col,
    _Float16* __restrict__ Wh,
    float* __restrict__ f_dst,
    float* __restrict__ f_row,
    int* __restrict__ gcur,
    unsigned* __restrict__ gstage) {
  __shared__ char smem[2 * 128 * LDSK * 2];  // 36864 B arena
  if (blockIdx.x < GEMM_BLOCKS) {
    // ---- GEMM part: Wh(fp16) = bf16(x) @ Wt^T + bias
    short* As = (short*)smem;
    short* Bs = As + 128 * LDSK;
    const int tid = threadIdx.x;
    const int lane = tid & 63;
    const int w = tid >> 6;
    const int wm = w >> 1, wn = w & 1;
    const int m0 = (blockIdx.x >> 1) * 128;
    const int n0 = (blockIdx.x & 1) * 128;
    f32x4 acc[4][4] = {{{0.f, 0.f, 0.f, 0.f}}};
    const int srow = tid >> 3;   // 0..31
    const int schunk = tid & 7;  // 0..7
    for (int k0 = 0; k0 < F; k0 += 64) {
#pragma unroll
      for (int i = 0; i < 4; ++i) {
        int r = i * 32 + srow;
        int gm = m0 + r; if (gm > N_NODES - 1) gm = N_NODES - 1;
        const float* src = x + (size_t)gm * F + k0 + schunk * 8;
        float4 lo = *(const float4*)src;
        float4 hi = *(const float4*)(src + 4);
        bf16x8 v;
        v[0] = (short)f2bf(lo.x); v[1] = (short)f2bf(lo.y);
        v[2] = (short)f2bf(lo.z); v[3] = (short)f2bf(lo.w);
        v[4] = (short)f2bf(hi.x); v[5] = (short)f2bf(hi.y);
        v[6] = (short)f2bf(hi.z); v[7] = (short)f2bf(hi.w);
        *(bf16x8*)&As[r * LDSK + schunk * 8] = v;
        *(bf16x8*)&Bs[r * LDSK + schunk * 8] =
            *(const bf16x8*)(Wt + (size_t)(n0 + r) * F + k0 + schunk * 8);
      }
      __syncthreads();
#pragma unroll
      for (int kk = 0; kk < 64; kk += 32) {
        const int rowsel = lane & 15;
        const int ksel = kk + (lane >> 4) * 8;
        bf16x8 af[4], bfr[4];
#pragma unroll
        for (int t = 0; t < 4; ++t) {
          af[t] = *(bf16x8*)&As[(wm * 64 + t * 16 + rowsel) * LDSK + ksel];
          bfr[t] = *(bf16x8*)&Bs[(wn * 64 + t * 16 + rowsel) * LDSK + ksel];
        }
#pragma unroll
        for (int mi = 0; mi < 4; ++mi)
#pragma unroll
          for (int nj = 0; nj < 4; ++nj)
            acc[mi][nj] = __builtin_amdgcn_mfma_f32_16x16x32_bf16(
                af[mi], bfr[nj], acc[mi][nj], 0, 0, 0);
      }
      __syncthreads();
    }
    const int crow = (lane >> 4) * 4;
    const int ccol = lane & 15;
#pragma unroll
    for (int nj = 0; nj < 4; ++nj) {
      int gc = n0 + wn * 64 + nj * 16 + ccol;
      float bv = bias[gc];
#pragma unroll
      for (int mi = 0; mi < 4; ++mi) {
        int gr = m0 + wm * 64 + mi * 16 + crow;
#pragma unroll
        for (int r = 0; r < 4; ++r)
          Wh[(size_t)(gr + r) * F + gc] = (_Float16)(acc[mi][nj][r] + bv);
      }
    }
    return;
  }
  if (blockIdx.x < GEMM_BLOCKS + NAB) {
    // ---- binA2 part
    int* h = (int*)smem;
    int* lofs = h + NB;
    int* lcur = lofs + NB;
    int* gb = lcur + NB;
    unsigned* stage = (unsigned*)(gb + NB);  // EPB entries
    const int t = threadIdx.x;
    for (int i = t; i < NB; i += 256) { h[i] = 0; lcur[i] = 0; }
    __syncthreads();
    const int base = (blockIdx.x - GEMM_BLOCKS) * EPB;
    const int cnt = min(EPB, N_EDGES - base);
#pragma unroll
    for (int j = 0; j < 16; ++j) {
      int k = base + j * 256 + t;
      if (k < N_EDGES) atomicAdd(&h[row[k] >> 8], 1);
    }
    __syncthreads();
    if (t == 0) {
      int run = 0;
      for (int i = 0; i < NB; ++i) { lofs[i] = run; run += h[i]; }
    }
    __syncthreads();
    if (t < NB && h[t] > 0) gb[t] = atomicAdd(&gcur[t], h[t]);
    __syncthreads();
#pragma unroll
    for (int j = 0; j < 16; ++j) {
      int k = base + j * 256 + t;
      if (k < N_EDGES) {
        int r = row[k], b = r >> 8;
        int lp = lofs[b] + atomicAdd(&lcur[b], 1);
        stage[lp] = ((unsigned)b << 24) | ((unsigned)(r & 255) << 16) |
                    (unsigned)col[k];
      }
    }
    __syncthreads();
#pragma unroll
    for (int j = 0; j < 16; ++j) {
      int s = j * 256 + t;
      if (s < cnt) {
        unsigned wv = stage[s];
        int b = wv >> 24;
        gstage[(size_t)b * CAP + gb[b] + (s - lofs[b])] = wv & 0x00FFFFFFu;
      }
    }
    return;
  }
  // ---- fvec part: grid-stride fat blocks (4 nodes/iter/block)
  const int lane = threadIdx.x & 63, w = threadIdx.x >> 6;
  const int slot = blockIdx.x - GEMM_BLOCKS - NAB;
  float4 v1 = *(const float4*)(wa + lane * 4);
  float4 v2 = *(const float4*)(wa + F + lane * 4);
  for (int node = slot * 4 + w; node < N_NODES; node += FVEC_SLOTS * 4) {
    float4 xv = *(const float4*)(x + (size_t)node * F + lane * 4);
    float s1 = xv.x * v1.x + xv.y * v1.y + xv.z * v1.z + xv.w * v1.w;
    float s2 = xv.x * v2.x + xv.y * v2.y + xv.z * v2.z + xv.w * v2.w;
#pragma unroll
    for (int off = 32; off > 0; off >>= 1) {
      s1 += __shfl_down(s1, off, 64);
      s2 += __shfl_down(s2, off, 64);
    }
    if (lane == 0) { f_dst[node] = s1; f_row[node] = s2; }
  }
}

// ---- L3: binB (512 thr): per-(row,colbin) histogram -> entries placed
// APPROXIMATELY COL-SORTED within each row (8 bins, q = col>>13) so pull's
// gathers sweep the Wh table in phase -> L2 working set ~4.2 MB per phase.
__global__ __launch_bounds__(512) void binB(const int* __restrict__ gcur,
                                            const unsigned* __restrict__ gstage,
                                            const float* __restrict__ f_dst,
                                            const float* __restrict__ f_row,
                                            const float* __restrict__ cb,
                                            int2* __restrict__ rsc,
                                            float* __restrict__ inv_denom,
                                            unsigned* __restrict__ csr) {
  __shared__ int cnt2[2048];  // per (row, colbin)
  __shared__ int cur2[2048];
  __shared__ int rcnt[256], rbase[256];
  __shared__ float dsum[256];
  const int t = threadIdx.x;
  const int b = blockIdx.x;
  for (int i = t; i < 2048; i += 512) cnt2[i] = 0;
  if (t < 256) dsum[t] = 0.f;
  __syncthreads();
  const int nb = gcur[b];
  const int start = b * CAP;
  const float cbs = cb[0];
  for (int s = t; s < nb; s += 512) {
    unsigned wv = gstage[start + s];
    int key = (((wv >> 16) & 255) << 3) | ((wv & 0xFFFFu) >> 13);
    atomicAdd(&cnt2[key], 1);
  }
  __syncthreads();
  if (t < 256) {
    int tot = 0;
#pragma unroll
    for (int q = 0; q < 8; ++q) tot += cnt2[t * 8 + q];
    rcnt[t] = tot;
  }
  __syncthreads();
  if (t == 0) {
    int run = 0;
    for (int i = 0; i < 256; ++i) { rbase[i] = run; run += rcnt[i]; }
  }
  __syncthreads();
  if (t < 256) {
    int base = start + rbase[t];
    int g = (b << 8) + t;
    if (g < N_NODES) rsc[g] = make_int2(base, rcnt[t]);
    int run = base;
#pragma unroll
    for (int q = 0; q < 8; ++q) { cur2[t * 8 + q] = run; run += cnt2[t * 8 + q]; }
  }
  __syncthreads();
  for (int s = t; s < nb; s += 512) {
    unsigned wv = gstage[start + s];
    int lr = (wv >> 16) & 255;
    int c = wv & 0xFFFF;
    float ev = f_dst[c] + f_row[(b << 8) + lr] + cbs;
    ev = ev > 0.f ? ev : ALPHA * ev;
    float ex = __expf(ev);
    int p = atomicAdd(&cur2[(lr << 3) | (c >> 13)], 1);  // absolute index
    csr[p] = ((unsigned)f2h_bits(ex) << 16) | (unsigned)c;
    atomicAdd(&dsum[lr], ex);
  }
  __syncthreads();
  if (t < 256) {
    int g = (b << 8) + t;
    if (g < N_NODES) inv_denom[g] = (rcnt[t] > 0) ? (1.0f / dsum[t]) : 0.f;
  }
}

// ---- L4: pull: unrolled gather; weights + denom pre-baked; (start,count).
__global__ __launch_bounds__(256) void gat_pull(const int2* __restrict__ rsc,
                                                const unsigned* __restrict__ csr,
                                                const float* __restrict__ inv_denom,
                                                const _Float16* __restrict__ Wh,
                                                float* __restrict__ out) {
  const int lane = threadIdx.x & 63, w = threadIdx.x >> 6;
  const int i = blockIdx.x * 4 + w;
  if (i >= N_NODES) return;
  const int2 rc = rsc[i];
  const int s = rc.x, e = rc.x + rc.y;
  const char* whb = (const char*)Wh;
  const unsigned laneoff = (unsigned)lane * 8u;
  float4 acc = make_float4(0.f, 0.f, 0.f, 0.f);
  for (int p = s; p < e; p += UNROLL) {
    unsigned wv[UNROLL];
#pragma unroll
    for (int j = 0; j < UNROLL; ++j) {
      int q = p + j;
      wv[j] = csr[q < e ? q : s];  // clamp: redundant loads hit L1
    }
    half4 v[UNROLL];
#pragma unroll
    for (int j = 0; j < UNROLL; ++j) {
      unsigned off = (wv[j] & 0xFFFFu) * 512u + laneoff;  // 32-bit addressing
      v[j] = *(const half4*)(whb + off);
    }
#pragma unroll
    for (int j = 0; j < UNROLL; ++j) {
      float xw = h_bits2f((unsigned short)(wv[j] >> 16));
      xw = (p + j < e) ? xw : 0.f;
      acc.x += xw * (float)v[j][0];
      acc.y += xw * (float)v[j][1];
      acc.z += xw * (float)v[j][2];
      acc.w += xw * (float)v[j][3];
    }
  }
  const float inv = inv_denom[i];
  acc.x = fmaxf(acc.x * inv, 0.f); acc.y = fmaxf(acc.y * inv, 0.f);
  acc.z = fmaxf(acc.z * inv, 0.f); acc.w = fmaxf(acc.w * inv, 0.f);
  ((float4*)out)[(size_t)i * 64 + lane] = acc;
}

extern "C" void kernel_launch(void* const* d_in, const int* in_sizes, int n_in,
                              void* d_out, int out_size, void* d_ws, size_t ws_size,
                              hipStream_t stream) {
  const float* x   = (const float*)d_in[0];
  const float* W_w = (const float*)d_in[1];
  const float* W_b = (const float*)d_in[2];
  const float* a_w = (const float*)d_in[3];
  const float* a_b = (const float*)d_in[4];
  const int*   row = (const int*)d_in[5];
  const int*   col = (const int*)d_in[6];
  float* out = (float*)d_out;

  float* ws = (float*)d_ws;
  size_t off = 0;
  _Float16* Wh = (_Float16*)(ws + off); off += (size_t)NP * F / 2;       // fp16
  unsigned short* Wt = (unsigned short*)(ws + off); off += (F * F) / 2;  // bf16
  float* wa = ws + off;            off += 2 * F;
  float* cb = ws + off;            off += 8;
  float* f_dst = ws + off;         off += NP;
  float* f_row = ws + off;         off += NP;
  int* gcur = (int*)(ws + off);    off += NB;
  int2* rsc = (int2*)(ws + off);   off += 2 * (size_t)NP;
  float* inv_denom = (float*)(ws + off); off += NP;
  unsigned* gstage = (unsigned*)(ws + off); off += (size_t)NB * CAP;
  unsigned* csr = (unsigned*)(ws + off); off += (size_t)NB * CAP;
  (void)ws_size; (void)in_sizes; (void)n_in; (void)out_size;

  hipLaunchKernelGGL(prep_w, dim3(65), dim3(256), 0, stream, W_w, a_w, W_b,
                     a_b, Wt, wa, cb, gcur);
  hipLaunchKernelGGL(gemm_fvec_binA2, dim3(GEMM_BLOCKS + NAB + FVEC_SLOTS),
                     dim3(256), 0, stream, x, Wt, W_b, wa, row, col, Wh,
                     f_dst, f_row, gcur, gstage);
  hipLaunchKernelGGL(binB, dim3(NB), dim3(512), 0, stream, gcur, gstage,
                     f_dst, f_row, cb, rsc, inv_denom, csr);
  hipLaunchKernelGGL(gat_pull, dim3((N_NODES + 3) / 4), dim3(256), 0, stream,
                     rsc, csr, inv_denom, Wh, out);
}